// Round 1
// baseline (2331.178 us; speedup 1.0000x reference)
//
#include <hip/hip_runtime.h>
#include <stdint.h>

#define BATCH 16
#define NA 9
#define HH 128
#define WW 128
#define HW (HH*WW)            // 16384
#define NITEMS (NA*HW)        // 147456 per batch
#define PRE 6000
#define POST 300
#define NMS_T 0.7f
#define NBINS 65536
#define CAP 8192

__device__ __forceinline__ uint32_t fkey(float f) {
    uint32_t u = __float_as_uint(f);
    return u ^ ((u & 0x80000000u) ? 0xFFFFFFFFu : 0x80000000u);
}

// K1: per-batch histogram of top-16 key bits over fg scores
__global__ void k_hist(const float* __restrict__ scores, uint32_t* __restrict__ hist) {
    int gid = blockIdx.x * blockDim.x + threadIdx.x;
    if (gid >= BATCH * NITEMS) return;
    int b = gid / NITEMS;
    int rem = gid - b * NITEMS;               // spans channels NA..2NA-1 linearly
    float s = scores[(size_t)b * (2 * NA * HW) + (size_t)NA * HW + rem];
    atomicAdd(&hist[b * NBINS + (fkey(s) >> 16)], 1u);
}

// K2: find bucket where cumulative-from-top crosses PRE
__global__ void k_findbucket(const uint32_t* __restrict__ hist, uint32_t* __restrict__ bucket) {
    int b = blockIdx.x;
    const uint32_t* hb = hist + (size_t)b * NBINS;
    __shared__ uint32_t csum[256];
    __shared__ uint32_t csuf[257];
    int t = threadIdx.x;            // 256 threads, 256 bins each
    uint32_t s = 0;
    for (int u = 0; u < 256; ++u) s += hb[t * 256 + u];
    csum[t] = s;
    __syncthreads();
    if (t == 0) {
        uint32_t acc = 0;
        csuf[256] = 0;
        for (int c = 255; c >= 0; --c) { acc += csum[c]; csuf[c] = acc; }
    }
    __syncthreads();
    uint32_t cum = csuf[t + 1];     // count of items in bins strictly above this chunk
    for (int u = 255; u >= 0; --u) {
        uint32_t c = hb[t * 256 + u];
        if (cum < PRE && cum + c >= PRE) bucket[b] = (uint32_t)(t * 256 + u);
        cum += c;
    }
}

// K3: compact (key, idx) pairs with key-bucket >= threshold bucket
__global__ void k_compact(const float* __restrict__ scores, const uint32_t* __restrict__ bucket,
                          uint32_t* __restrict__ cnt, unsigned long long* __restrict__ pairs) {
    int gid = blockIdx.x * blockDim.x + threadIdx.x;
    if (gid >= BATCH * NITEMS) return;
    int b = gid / NITEMS;
    int rem = gid - b * NITEMS;
    int c = rem / HW;           // anchor channel 0..8
    int pix = rem - c * HW;     // h*W + w
    float s = scores[(size_t)b * (2 * NA * HW) + (size_t)(NA + c) * HW + pix];
    uint32_t k = fkey(s);
    if ((k >> 16) >= bucket[b]) {
        uint32_t pos = atomicAdd(&cnt[b], 1u);
        if (pos < CAP) {
            uint32_t idx = (uint32_t)(pix * NA + c);   // flat (h,w,a) item index
            pairs[(size_t)b * CAP + pos] = ((unsigned long long)k << 32) | (uint32_t)(~idx);
        }
    }
}

// K4: per-batch bitonic sort (descending) of up to 8192 packed keys; emit top PRE indices
__global__ __launch_bounds__(1024) void k_sort(const unsigned long long* __restrict__ pairs,
                                               const uint32_t* __restrict__ cnt,
                                               uint32_t* __restrict__ sidx) {
    int b = blockIdx.x;
    __shared__ unsigned long long s[CAP];
    int t = threadIdx.x;
    uint32_t n = cnt[b];
    if (n > CAP) n = CAP;
    for (int e = t; e < CAP; e += 1024)
        s[e] = (e < (int)n) ? pairs[(size_t)b * CAP + e] : 0ull;
    __syncthreads();
    for (int k = 2; k <= CAP; k <<= 1) {
        for (int j = k >> 1; j > 0; j >>= 1) {
            for (int p = t; p < CAP / 2; p += 1024) {
                int i = 2 * p - (p & (j - 1));
                int ix = i | j;
                unsigned long long a = s[i], c = s[ix];
                bool up = ((i & k) == 0);
                if ((a < c) == up) { s[i] = c; s[ix] = a; }
            }
            __syncthreads();
        }
    }
    for (int e = t; e < PRE; e += 1024)
        sidx[(size_t)b * PRE + e] = ~((uint32_t)s[e]);
}

// K5: decode + clip proposals for the top PRE items per batch
__global__ void k_proposals(const float* __restrict__ deltas, const float* __restrict__ im_info,
                            const float* __restrict__ anchors, const uint32_t* __restrict__ sidx,
                            float4* __restrict__ boxes) {
#pragma clang fp contract(off)
    int gid = blockIdx.x * blockDim.x + threadIdx.x;
    if (gid >= BATCH * PRE) return;
    int b = gid / PRE;
    int idx = (int)sidx[gid];
    int a = idx % NA;
    int cell = idx / NA;
    int wx = cell & (WW - 1);
    int hy = cell >> 7;
    const float* D = deltas + (size_t)b * (4 * NA * HW) + (size_t)(4 * a) * HW + hy * WW + wx;
    float dx = D[0], dy = D[HW], dw = D[2 * HW], dh = D[3 * HW];
    float ax1 = anchors[4 * a + 0], ay1 = anchors[4 * a + 1];
    float ax2 = anchors[4 * a + 2], ay2 = anchors[4 * a + 3];
    float sx = (float)(wx * 16), sy = (float)(hy * 16);
    float x1 = ax1 + sx, y1 = ay1 + sy, x2 = ax2 + sx, y2 = ay2 + sy;  // exact ints
    float w = x2 - x1 + 1.0f;
    float h = y2 - y1 + 1.0f;
    float cx = x1 + 0.5f * w;        // exact
    float cy = y1 + 0.5f * h;
    float pcx = dx * w + cx;         // contract(off): mul then add, matches XLA
    float pcy = dy * h + cy;
    float pw = (float)exp((double)dw) * w;   // ~correctly-rounded f32 exp
    float ph = (float)exp((double)dh) * h;
    float px1 = pcx - 0.5f * pw;
    float py1 = pcy - 0.5f * ph;
    float px2 = pcx + 0.5f * pw;
    float py2 = pcy + 0.5f * ph;
    float limx = im_info[b * 3 + 1] - 1.0f;
    float limy = im_info[b * 3 + 0] - 1.0f;
    px1 = fminf(fmaxf(px1, 0.0f), limx);
    py1 = fminf(fmaxf(py1, 0.0f), limy);
    px2 = fminf(fmaxf(px2, 0.0f), limx);
    py2 = fminf(fmaxf(py2, 0.0f), limy);
    boxes[gid] = make_float4(px1, py1, px2, py2);
}

// K6: greedy NMS entirely in LDS, early-exit at POST kept; write output
__global__ __launch_bounds__(1024) void k_nms(const float4* __restrict__ boxes,
                                              float* __restrict__ out) {
#pragma clang fp contract(off)
    int b = blockIdx.x;
    int t = threadIdx.x;
    __shared__ float4 sb[PRE];            // 96000 B
    __shared__ float sarea[PRE];          // 24000 B
    __shared__ unsigned char skeep[PRE];  //  6000 B
    __shared__ int slist[POST];           //  1200 B
    for (int e = t; e < PRE; e += 1024) {
        float4 v = boxes[(size_t)b * PRE + e];
        sb[e] = v;
        sarea[e] = (v.z - v.x + 1.0f) * (v.w - v.y + 1.0f);
        skeep[e] = 1;
    }
    __syncthreads();
    int kept = 0;
    for (int i = 0; i < PRE && kept < POST; ++i) {
        if (skeep[i]) {               // uniform read (LDS broadcast)
            float4 bi = sb[i];
            float ai = sarea[i];
            for (int j = i + 1 + t; j < PRE; j += 1024) {
                if (!skeep[j]) continue;
                float4 bj = sb[j];
                float iw = fminf(bi.z, bj.z) - fmaxf(bi.x, bj.x) + 1.0f;
                float ih = fminf(bi.w, bj.w) - fmaxf(bi.y, bj.y) + 1.0f;
                iw = fmaxf(iw, 0.0f);
                ih = fmaxf(ih, 0.0f);
                float inter = iw * ih;
                float iou = inter / ((ai + sarea[j]) - inter);
                if (iou > NMS_T) skeep[j] = 0;
            }
            if (t == 0) slist[kept] = i;
            kept++;
            __syncthreads();
        }
    }
    __syncthreads();
    for (int k = t; k < POST; k += 1024) {
        float4 v = make_float4(0.f, 0.f, 0.f, 0.f);
        if (k < kept) v = sb[slist[k]];
        float* o = out + ((size_t)b * POST + k) * 5;
        o[0] = (float)b;
        o[1] = v.x; o[2] = v.y; o[3] = v.z; o[4] = v.w;
    }
}

extern "C" void kernel_launch(void* const* d_in, const int* in_sizes, int n_in,
                              void* d_out, int out_size, void* d_ws, size_t ws_size,
                              hipStream_t stream) {
    const float* scores  = (const float*)d_in[0];
    const float* deltas  = (const float*)d_in[1];
    const float* im_info = (const float*)d_in[2];
    const float* anchors = (const float*)d_in[3];
    float* out = (float*)d_out;

    char* ws = (char*)d_ws;
    const size_t HIST_B   = (size_t)BATCH * NBINS * 4;           // 4194304
    const size_t CNT_B    = 64;
    const size_t BKT_B    = 64;
    uint32_t* hist  = (uint32_t*)ws;
    uint32_t* cnt   = (uint32_t*)(ws + HIST_B);
    uint32_t* bkt   = (uint32_t*)(ws + HIST_B + CNT_B);
    unsigned long long* pairs = (unsigned long long*)(ws + HIST_B + CNT_B + BKT_B);
    const size_t PAIRS_B  = (size_t)BATCH * CAP * 8;             // 1048576
    uint32_t* sidx  = (uint32_t*)(ws + HIST_B + CNT_B + BKT_B + PAIRS_B);
    const size_t SIDX_B   = (size_t)BATCH * PRE * 4;             // 384000
    float4* boxes   = (float4*)(ws + HIST_B + CNT_B + BKT_B + PAIRS_B + SIDX_B);

    hipMemsetAsync(ws, 0, HIST_B + CNT_B + BKT_B, stream);

    int total = BATCH * NITEMS;
    k_hist<<<(total + 255) / 256, 256, 0, stream>>>(scores, hist);
    k_findbucket<<<BATCH, 256, 0, stream>>>(hist, bkt);
    k_compact<<<(total + 255) / 256, 256, 0, stream>>>(scores, bkt, cnt, pairs);
    k_sort<<<BATCH, 1024, 0, stream>>>(pairs, cnt, sidx);
    k_proposals<<<(BATCH * PRE + 255) / 256, 256, 0, stream>>>(deltas, im_info, anchors, sidx, boxes);
    k_nms<<<BATCH, 1024, 0, stream>>>(boxes, out);
}

// Round 2
// 682.637 us; speedup vs baseline: 3.4150x; 3.4150x over previous
//
#include <hip/hip_runtime.h>
#include <stdint.h>

#define BATCH 16
#define NA 9
#define HH 128
#define WW 128
#define HW (HH*WW)            // 16384
#define NITEMS (NA*HW)        // 147456 per batch
#define PRE 6000
#define POST 300
#define NMS_T 0.7f
#define NBINS 4096            // top-12 bits of sortable key
#define NSLICE 16             // histogram slices per batch
#define CAP 8192
#define CBLK 144              // compact blocks per batch (1024 items each)

__device__ __forceinline__ uint32_t fkey(float f) {
    uint32_t u = __float_as_uint(f);
    return u ^ ((u & 0x80000000u) ? 0xFFFFFFFFu : 0x80000000u);
}

// K1: per-(batch,slice) LDS histogram of top-12 key bits; non-atomic global write
__global__ __launch_bounds__(1024) void k_hist(const float4* __restrict__ scores4,
                                               uint32_t* __restrict__ hist) {
    int b = blockIdx.x / NSLICE;
    int sl = blockIdx.x % NSLICE;
    int t = threadIdx.x;
    __shared__ uint32_t lh[NBINS];
    for (int i = t; i < NBINS; i += 1024) lh[i] = 0;
    __syncthreads();
    size_t base4 = ((size_t)b * (2 * NA * HW) + (size_t)NA * HW) / 4;
    const int PER = NITEMS / NSLICE / 4;          // 2304 float4 per slice
    size_t s4 = base4 + (size_t)sl * PER;
    for (int v = t; v < PER; v += 1024) {
        float4 f = scores4[s4 + v];
        atomicAdd(&lh[fkey(f.x) >> 20], 1u);
        atomicAdd(&lh[fkey(f.y) >> 20], 1u);
        atomicAdd(&lh[fkey(f.z) >> 20], 1u);
        atomicAdd(&lh[fkey(f.w) >> 20], 1u);
    }
    __syncthreads();
    uint32_t* o = hist + ((size_t)b * NSLICE + sl) * NBINS;
    for (int i = t; i < NBINS; i += 1024) o[i] = lh[i];
}

// K2: merge slices, find bucket where cumulative-from-top crosses PRE
__global__ void k_findbucket(const uint32_t* __restrict__ hist, uint32_t* __restrict__ bucket) {
    int b = blockIdx.x;
    int t = threadIdx.x;                          // 256 threads, 16 bins each
    __shared__ uint32_t csum[256];
    __shared__ uint32_t csuf[257];
    const uint32_t* hb = hist + (size_t)b * NSLICE * NBINS;
    uint32_t binv[16];
    uint32_t s = 0;
    for (int u = 0; u < 16; ++u) {
        uint32_t v = 0;
        for (int sl = 0; sl < NSLICE; ++sl) v += hb[(size_t)sl * NBINS + t * 16 + u];
        binv[u] = v; s += v;
    }
    csum[t] = s;
    __syncthreads();
    if (t == 0) {
        uint32_t acc = 0;
        csuf[256] = 0;
        for (int c = 255; c >= 0; --c) { acc += csum[c]; csuf[c] = acc; }
    }
    __syncthreads();
    uint32_t cum = csuf[t + 1];
    for (int u = 15; u >= 0; --u) {
        uint32_t c = binv[u];
        if (cum < PRE && cum + c >= PRE) bucket[b] = (uint32_t)(t * 16 + u);
        cum += c;
    }
}

// K3: compact (key, idx) pairs with bucket >= threshold; ONE global atomic per block
__global__ __launch_bounds__(256) void k_compact(const float4* __restrict__ scores4,
                                                 const uint32_t* __restrict__ bucket,
                                                 uint32_t* __restrict__ cnt,
                                                 unsigned long long* __restrict__ pairs) {
    int b = blockIdx.x / CBLK;
    int blk = blockIdx.x % CBLK;
    int t = threadIdx.x;
    int lane = t & 63, wid = t >> 6;
    uint32_t bkt = bucket[b];
    size_t base4 = ((size_t)b * (2 * NA * HW) + (size_t)NA * HW) / 4;
    float4 f = scores4[base4 + (size_t)blk * 256 + t];
    int item0 = blk * 1024 + t * 4;               // first of this thread's 4 items
    uint32_t k0 = fkey(f.x), k1 = fkey(f.y), k2 = fkey(f.z), k3 = fkey(f.w);
    bool p0 = (k0 >> 20) >= bkt, p1 = (k1 >> 20) >= bkt;
    bool p2 = (k2 >> 20) >= bkt, p3 = (k3 >> 20) >= bkt;
    unsigned long long m0 = __ballot(p0), m1 = __ballot(p1);
    unsigned long long m2 = __ballot(p2), m3 = __ballot(p3);
    uint32_t c0 = (uint32_t)__popcll(m0), c1 = (uint32_t)__popcll(m1);
    uint32_t c2 = (uint32_t)__popcll(m2), c3 = (uint32_t)__popcll(m3);
    uint32_t wcnt = c0 + c1 + c2 + c3;
    __shared__ uint32_t swc[4];
    __shared__ uint32_t sbase;
    if (lane == 0) swc[wid] = wcnt;
    __syncthreads();
    if (t == 0) {
        uint32_t a0 = swc[0], a1 = swc[1], a2 = swc[2], a3 = swc[3];
        uint32_t tot = a0 + a1 + a2 + a3;
        sbase = tot ? atomicAdd(&cnt[b], tot) : 0u;
        swc[0] = 0; swc[1] = a0; swc[2] = a0 + a1; swc[3] = a0 + a1 + a2;
    }
    __syncthreads();
    uint32_t wbase = sbase + swc[wid];
    unsigned long long below = ((unsigned long long)1 << lane) - 1ull;
    unsigned long long* pb = pairs + (size_t)b * CAP;
#define EMIT(J, K, POS) do { \
        int rem = item0 + (J); \
        int c = rem / HW; \
        int pix = rem - c * HW; \
        uint32_t idx = (uint32_t)(pix * NA + c); \
        uint32_t pos_ = (POS); \
        if (pos_ < CAP) pb[pos_] = ((unsigned long long)(K) << 32) | (uint32_t)(~idx); \
    } while (0)
    if (p0) EMIT(0, k0, wbase + (uint32_t)__popcll(m0 & below));
    if (p1) EMIT(1, k1, wbase + c0 + (uint32_t)__popcll(m1 & below));
    if (p2) EMIT(2, k2, wbase + c0 + c1 + (uint32_t)__popcll(m2 & below));
    if (p3) EMIT(3, k3, wbase + c0 + c1 + c2 + (uint32_t)__popcll(m3 & below));
#undef EMIT
}

// K4: per-batch bitonic sort (descending) of up to 8192 packed keys; emit top PRE indices
__global__ __launch_bounds__(1024) void k_sort(const unsigned long long* __restrict__ pairs,
                                               const uint32_t* __restrict__ cnt,
                                               uint32_t* __restrict__ sidx) {
    int b = blockIdx.x;
    __shared__ unsigned long long s[CAP];
    int t = threadIdx.x;
    uint32_t n = cnt[b];
    if (n > CAP) n = CAP;
    for (int e = t; e < CAP; e += 1024)
        s[e] = (e < (int)n) ? pairs[(size_t)b * CAP + e] : 0ull;
    __syncthreads();
    for (int k = 2; k <= CAP; k <<= 1) {
        for (int j = k >> 1; j > 0; j >>= 1) {
            for (int p = t; p < CAP / 2; p += 1024) {
                int i = 2 * p - (p & (j - 1));
                int ix = i | j;
                unsigned long long a = s[i], c = s[ix];
                bool up = ((i & k) == 0);
                if ((a < c) == up) { s[i] = c; s[ix] = a; }
            }
            __syncthreads();
        }
    }
    for (int e = t; e < PRE; e += 1024)
        sidx[(size_t)b * PRE + e] = ~((uint32_t)s[e]);
}

// K5: decode + clip proposals for the top PRE items per batch
__global__ void k_proposals(const float* __restrict__ deltas, const float* __restrict__ im_info,
                            const float* __restrict__ anchors, const uint32_t* __restrict__ sidx,
                            float4* __restrict__ boxes) {
#pragma clang fp contract(off)
    int gid = blockIdx.x * blockDim.x + threadIdx.x;
    if (gid >= BATCH * PRE) return;
    int b = gid / PRE;
    int idx = (int)sidx[gid];
    int a = idx % NA;
    int cell = idx / NA;
    int wx = cell & (WW - 1);
    int hy = cell >> 7;
    const float* D = deltas + (size_t)b * (4 * NA * HW) + (size_t)(4 * a) * HW + hy * WW + wx;
    float dx = D[0], dy = D[HW], dw = D[2 * HW], dh = D[3 * HW];
    float ax1 = anchors[4 * a + 0], ay1 = anchors[4 * a + 1];
    float ax2 = anchors[4 * a + 2], ay2 = anchors[4 * a + 3];
    float sx = (float)(wx * 16), sy = (float)(hy * 16);
    float x1 = ax1 + sx, y1 = ay1 + sy, x2 = ax2 + sx, y2 = ay2 + sy;
    float w = x2 - x1 + 1.0f;
    float h = y2 - y1 + 1.0f;
    float cx = x1 + 0.5f * w;
    float cy = y1 + 0.5f * h;
    float pcx = dx * w + cx;
    float pcy = dy * h + cy;
    float pw = (float)exp((double)dw) * w;
    float ph = (float)exp((double)dh) * h;
    float px1 = pcx - 0.5f * pw;
    float py1 = pcy - 0.5f * ph;
    float px2 = pcx + 0.5f * pw;
    float py2 = pcy + 0.5f * ph;
    float limx = im_info[b * 3 + 1] - 1.0f;
    float limy = im_info[b * 3 + 0] - 1.0f;
    px1 = fminf(fmaxf(px1, 0.0f), limx);
    py1 = fminf(fmaxf(py1, 0.0f), limy);
    px2 = fminf(fmaxf(px2, 0.0f), limx);
    py2 = fminf(fmaxf(py2, 0.0f), limy);
    boxes[gid] = make_float4(px1, py1, px2, py2);
}

// K6: greedy NMS; boxes/areas/alive in registers (fixed ownership), publish via LDS
__global__ __launch_bounds__(1024) void k_nms(const float4* __restrict__ boxes,
                                              float* __restrict__ out) {
#pragma clang fp contract(off)
    int b = blockIdx.x;
    int t = threadIdx.x;
    __shared__ float4 sb[PRE];            // 96000 B
    __shared__ float sarea[PRE];          // 24000 B
    __shared__ unsigned char skeep[PRE];  //  6000 B
    __shared__ int slist[POST];           //  1200 B
    float4 bx[6]; float ar[6]; bool alive[6];
#pragma unroll
    for (int m = 0; m < 6; ++m) {
        int e = t + m * 1024;
        alive[m] = false;
        if (e < PRE) {
            float4 v = boxes[(size_t)b * PRE + e];
            sb[e] = v;
            float a = (v.z - v.x + 1.0f) * (v.w - v.y + 1.0f);
            sarea[e] = a;
            skeep[e] = 1;
            bx[m] = v; ar[m] = a; alive[m] = true;
        }
    }
    __syncthreads();
    int kept = 0;
    for (int i = 0; i < PRE && kept < POST; ++i) {
        if (skeep[i]) {                   // uniform LDS broadcast
            float4 bi = sb[i];
            float ai = sarea[i];
#pragma unroll
            for (int m = 0; m < 6; ++m) {
                int j = t + m * 1024;
                if (alive[m] && j > i) {
                    float iw = fminf(bi.z, bx[m].z) - fmaxf(bi.x, bx[m].x) + 1.0f;
                    float ih = fminf(bi.w, bx[m].w) - fmaxf(bi.y, bx[m].y) + 1.0f;
                    iw = fmaxf(iw, 0.0f);
                    ih = fmaxf(ih, 0.0f);
                    float inter = iw * ih;
                    float iou = inter / ((ai + ar[m]) - inter);
                    if (iou > NMS_T) { alive[m] = false; skeep[j] = 0; }
                }
            }
            if (t == 0) slist[kept] = i;
            kept++;
            __syncthreads();
        }
    }
    __syncthreads();
    for (int k = t; k < POST; k += 1024) {
        float4 v = make_float4(0.f, 0.f, 0.f, 0.f);
        if (k < kept) v = sb[slist[k]];
        float* o = out + ((size_t)b * POST + k) * 5;
        o[0] = (float)b;
        o[1] = v.x; o[2] = v.y; o[3] = v.z; o[4] = v.w;
    }
}

extern "C" void kernel_launch(void* const* d_in, const int* in_sizes, int n_in,
                              void* d_out, int out_size, void* d_ws, size_t ws_size,
                              hipStream_t stream) {
    const float* scores  = (const float*)d_in[0];
    const float* deltas  = (const float*)d_in[1];
    const float* im_info = (const float*)d_in[2];
    const float* anchors = (const float*)d_in[3];
    float* out = (float*)d_out;

    char* ws = (char*)d_ws;
    const size_t HIST_B  = (size_t)BATCH * NSLICE * NBINS * 4;   // 4 MiB
    const size_t CNT_B   = 64;
    const size_t BKT_B   = 64;
    const size_t PAIRS_B = (size_t)BATCH * CAP * 8;              // 1 MiB
    const size_t SIDX_B  = (size_t)BATCH * PRE * 4;              // 384 KB
    uint32_t* hist = (uint32_t*)ws;
    uint32_t* cnt  = (uint32_t*)(ws + HIST_B);
    uint32_t* bkt  = (uint32_t*)(ws + HIST_B + CNT_B);
    unsigned long long* pairs = (unsigned long long*)(ws + HIST_B + CNT_B + BKT_B);
    uint32_t* sidx = (uint32_t*)(ws + HIST_B + CNT_B + BKT_B + PAIRS_B);
    float4* boxes  = (float4*)(ws + HIST_B + CNT_B + BKT_B + PAIRS_B + SIDX_B);

    hipMemsetAsync(cnt, 0, CNT_B, stream);

    k_hist<<<BATCH * NSLICE, 1024, 0, stream>>>((const float4*)scores, hist);
    k_findbucket<<<BATCH, 256, 0, stream>>>(hist, bkt);
    k_compact<<<BATCH * CBLK, 256, 0, stream>>>((const float4*)scores, bkt, cnt, pairs);
    k_sort<<<BATCH, 1024, 0, stream>>>(pairs, cnt, sidx);
    k_proposals<<<(BATCH * PRE + 255) / 256, 256, 0, stream>>>(deltas, im_info, anchors, sidx, boxes);
    k_nms<<<BATCH, 1024, 0, stream>>>(boxes, out);
}

// Round 3
// 228.569 us; speedup vs baseline: 10.1990x; 2.9866x over previous
//
#include <hip/hip_runtime.h>
#include <stdint.h>

#define BATCH 16
#define NA 9
#define HH 128
#define WW 128
#define HW (HH*WW)            // 16384
#define NITEMS (NA*HW)        // 147456 per batch
#define PRE 6000
#define POST 300
#define NMS_T 0.7f
#define NBINS 4096            // top-12 bits of sortable key
#define NSLICE 16             // histogram slices per batch
#define CAP 8192
#define CBLK 144              // compact blocks per batch (1024 items each)

__device__ __forceinline__ uint32_t fkey(float f) {
    uint32_t u = __float_as_uint(f);
    return u ^ ((u & 0x80000000u) ? 0xFFFFFFFFu : 0x80000000u);
}

// K1: per-(batch,slice) LDS histogram of top-12 key bits; non-atomic global write
__global__ __launch_bounds__(1024) void k_hist(const float4* __restrict__ scores4,
                                               uint32_t* __restrict__ hist) {
    int b = blockIdx.x / NSLICE;
    int sl = blockIdx.x % NSLICE;
    int t = threadIdx.x;
    __shared__ uint32_t lh[NBINS];
    for (int i = t; i < NBINS; i += 1024) lh[i] = 0;
    __syncthreads();
    size_t base4 = ((size_t)b * (2 * NA * HW) + (size_t)NA * HW) / 4;
    const int PER = NITEMS / NSLICE / 4;          // 2304 float4 per slice
    size_t s4 = base4 + (size_t)sl * PER;
    for (int v = t; v < PER; v += 1024) {
        float4 f = scores4[s4 + v];
        atomicAdd(&lh[fkey(f.x) >> 20], 1u);
        atomicAdd(&lh[fkey(f.y) >> 20], 1u);
        atomicAdd(&lh[fkey(f.z) >> 20], 1u);
        atomicAdd(&lh[fkey(f.w) >> 20], 1u);
    }
    __syncthreads();
    uint32_t* o = hist + ((size_t)b * NSLICE + sl) * NBINS;
    for (int i = t; i < NBINS; i += 1024) o[i] = lh[i];
}

// K2: merge slices, find bucket where cumulative-from-top crosses PRE
__global__ void k_findbucket(const uint32_t* __restrict__ hist, uint32_t* __restrict__ bucket) {
    int b = blockIdx.x;
    int t = threadIdx.x;                          // 256 threads, 16 bins each
    __shared__ uint32_t csum[256];
    __shared__ uint32_t csuf[257];
    const uint32_t* hb = hist + (size_t)b * NSLICE * NBINS;
    uint32_t binv[16];
    uint32_t s = 0;
    for (int u = 0; u < 16; ++u) {
        uint32_t v = 0;
        for (int sl = 0; sl < NSLICE; ++sl) v += hb[(size_t)sl * NBINS + t * 16 + u];
        binv[u] = v; s += v;
    }
    csum[t] = s;
    __syncthreads();
    if (t == 0) {
        uint32_t acc = 0;
        csuf[256] = 0;
        for (int c = 255; c >= 0; --c) { acc += csum[c]; csuf[c] = acc; }
    }
    __syncthreads();
    uint32_t cum = csuf[t + 1];
    for (int u = 15; u >= 0; --u) {
        uint32_t c = binv[u];
        if (cum < PRE && cum + c >= PRE) bucket[b] = (uint32_t)(t * 16 + u);
        cum += c;
    }
}

// K3: compact (key, idx) pairs with bucket >= threshold; ONE global atomic per block
__global__ __launch_bounds__(256) void k_compact(const float4* __restrict__ scores4,
                                                 const uint32_t* __restrict__ bucket,
                                                 uint32_t* __restrict__ cnt,
                                                 unsigned long long* __restrict__ pairs) {
    int b = blockIdx.x / CBLK;
    int blk = blockIdx.x % CBLK;
    int t = threadIdx.x;
    int lane = t & 63, wid = t >> 6;
    uint32_t bkt = bucket[b];
    size_t base4 = ((size_t)b * (2 * NA * HW) + (size_t)NA * HW) / 4;
    float4 f = scores4[base4 + (size_t)blk * 256 + t];
    int item0 = blk * 1024 + t * 4;               // first of this thread's 4 items
    uint32_t k0 = fkey(f.x), k1 = fkey(f.y), k2 = fkey(f.z), k3 = fkey(f.w);
    bool p0 = (k0 >> 20) >= bkt, p1 = (k1 >> 20) >= bkt;
    bool p2 = (k2 >> 20) >= bkt, p3 = (k3 >> 20) >= bkt;
    unsigned long long m0 = __ballot(p0), m1 = __ballot(p1);
    unsigned long long m2 = __ballot(p2), m3 = __ballot(p3);
    uint32_t c0 = (uint32_t)__popcll(m0), c1 = (uint32_t)__popcll(m1);
    uint32_t c2 = (uint32_t)__popcll(m2), c3 = (uint32_t)__popcll(m3);
    uint32_t wcnt = c0 + c1 + c2 + c3;
    __shared__ uint32_t swc[4];
    __shared__ uint32_t sbase;
    if (lane == 0) swc[wid] = wcnt;
    __syncthreads();
    if (t == 0) {
        uint32_t a0 = swc[0], a1 = swc[1], a2 = swc[2], a3 = swc[3];
        uint32_t tot = a0 + a1 + a2 + a3;
        sbase = tot ? atomicAdd(&cnt[b], tot) : 0u;
        swc[0] = 0; swc[1] = a0; swc[2] = a0 + a1; swc[3] = a0 + a1 + a2;
    }
    __syncthreads();
    uint32_t wbase = sbase + swc[wid];
    unsigned long long below = ((unsigned long long)1 << lane) - 1ull;
    unsigned long long* pb = pairs + (size_t)b * CAP;
#define EMIT(J, K, POS) do { \
        int rem = item0 + (J); \
        int c = rem / HW; \
        int pix = rem - c * HW; \
        uint32_t idx = (uint32_t)(pix * NA + c); \
        uint32_t pos_ = (POS); \
        if (pos_ < CAP) pb[pos_] = ((unsigned long long)(K) << 32) | (uint32_t)(~idx); \
    } while (0)
    if (p0) EMIT(0, k0, wbase + (uint32_t)__popcll(m0 & below));
    if (p1) EMIT(1, k1, wbase + c0 + (uint32_t)__popcll(m1 & below));
    if (p2) EMIT(2, k2, wbase + c0 + c1 + (uint32_t)__popcll(m2 & below));
    if (p3) EMIT(3, k3, wbase + c0 + c1 + c2 + (uint32_t)__popcll(m3 & below));
#undef EMIT
}

// K4: per-batch bitonic sort (descending) of up to 8192 packed keys; emit top PRE indices
__global__ __launch_bounds__(1024) void k_sort(const unsigned long long* __restrict__ pairs,
                                               const uint32_t* __restrict__ cnt,
                                               uint32_t* __restrict__ sidx) {
    int b = blockIdx.x;
    __shared__ unsigned long long s[CAP];
    int t = threadIdx.x;
    uint32_t n = cnt[b];
    if (n > CAP) n = CAP;
    for (int e = t; e < CAP; e += 1024)
        s[e] = (e < (int)n) ? pairs[(size_t)b * CAP + e] : 0ull;
    __syncthreads();
    for (int k = 2; k <= CAP; k <<= 1) {
        for (int j = k >> 1; j > 0; j >>= 1) {
            for (int p = t; p < CAP / 2; p += 1024) {
                int i = 2 * p - (p & (j - 1));
                int ix = i | j;
                unsigned long long a = s[i], c = s[ix];
                bool up = ((i & k) == 0);
                if ((a < c) == up) { s[i] = c; s[ix] = a; }
            }
            __syncthreads();
        }
    }
    for (int e = t; e < PRE; e += 1024)
        sidx[(size_t)b * PRE + e] = ~((uint32_t)s[e]);
}

// K5: decode + clip proposals for the top PRE items per batch
__global__ void k_proposals(const float* __restrict__ deltas, const float* __restrict__ im_info,
                            const float* __restrict__ anchors, const uint32_t* __restrict__ sidx,
                            float4* __restrict__ boxes) {
#pragma clang fp contract(off)
    int gid = blockIdx.x * blockDim.x + threadIdx.x;
    if (gid >= BATCH * PRE) return;
    int b = gid / PRE;
    int idx = (int)sidx[gid];
    int a = idx % NA;
    int cell = idx / NA;
    int wx = cell & (WW - 1);
    int hy = cell >> 7;
    const float* D = deltas + (size_t)b * (4 * NA * HW) + (size_t)(4 * a) * HW + hy * WW + wx;
    float dx = D[0], dy = D[HW], dw = D[2 * HW], dh = D[3 * HW];
    float ax1 = anchors[4 * a + 0], ay1 = anchors[4 * a + 1];
    float ax2 = anchors[4 * a + 2], ay2 = anchors[4 * a + 3];
    float sx = (float)(wx * 16), sy = (float)(hy * 16);
    float x1 = ax1 + sx, y1 = ay1 + sy, x2 = ax2 + sx, y2 = ay2 + sy;
    float w = x2 - x1 + 1.0f;
    float h = y2 - y1 + 1.0f;
    float cx = x1 + 0.5f * w;
    float cy = y1 + 0.5f * h;
    float pcx = dx * w + cx;
    float pcy = dy * h + cy;
    float pw = (float)exp((double)dw) * w;
    float ph = (float)exp((double)dh) * h;
    float px1 = pcx - 0.5f * pw;
    float py1 = pcy - 0.5f * ph;
    float px2 = pcx + 0.5f * pw;
    float py2 = pcy + 0.5f * ph;
    float limx = im_info[b * 3 + 1] - 1.0f;
    float limy = im_info[b * 3 + 0] - 1.0f;
    px1 = fminf(fmaxf(px1, 0.0f), limx);
    py1 = fminf(fmaxf(py1, 0.0f), limy);
    px2 = fminf(fmaxf(px2, 0.0f), limx);
    py2 = fminf(fmaxf(py2, 0.0f), limy);
    boxes[gid] = make_float4(px1, py1, px2, py2);
}

// K6: candidate-centric chunked greedy NMS (exact equivalent of row-wise greedy).
// 64 candidates per round: parallel test vs kept list, wave-0 in-register greedy
// among survivors via ballot masks, append. ~3 barriers/round, 4 waves.
__global__ __launch_bounds__(256) void k_nms(const float4* __restrict__ boxes,
                                             float* __restrict__ out) {
#pragma clang fp contract(off)
    const int b = blockIdx.x;
    const int t = threadIdx.x;
    const int cand = t & 63;
    const int slice = t >> 6;            // 0..3: strided slice of kept list
    __shared__ float4 kbox[POST + 64];   // kept boxes, index order
    __shared__ float  karea[POST + 64];
    __shared__ float4 cbx[64];
    __shared__ float  car[64];
    __shared__ unsigned char sup[64];
    __shared__ int skept;
    if (t == 0) skept = 0;
    __syncthreads();
    const int NR = (PRE + 63) / 64;      // 94
    for (int r = 0; r < NR; ++r) {
        int kept = skept;                // uniform
        if (kept >= POST) break;
        int c = r * 64 + cand;
        bool valid = (c < PRE);
        float4 cb;
        if (valid) cb = boxes[(size_t)b * PRE + c];
        else       cb = make_float4(0.f, 0.f, 0.f, 0.f);
        float ca = (cb.z - cb.x + 1.0f) * (cb.w - cb.y + 1.0f);
        if (t < 64) { cbx[t] = cb; car[t] = ca; sup[t] = valid ? 0 : 1; }
        __syncthreads();                 // B1: sup init visible
        for (int k = slice; k < kept; k += 4) {
            float4 kb = kbox[k];         // LDS broadcast
            float iwr = fminf(kb.z, cb.z) - fmaxf(kb.x, cb.x) + 1.0f;
            float ihr = fminf(kb.w, cb.w) - fmaxf(kb.y, cb.y) + 1.0f;
            if (iwr > 0.0f && ihr > 0.0f) {   // exact: else iou == 0
                float inter = iwr * ihr;
                float iou = inter / ((karea[k] + ca) - inter);
                if (iou > NMS_T) { sup[cand] = 1; break; }
            }
        }
        __syncthreads();                 // B2: kills visible
        if (t < 64) {                    // wave 0 only
            bool myal = (sup[t] == 0);
            unsigned long long rem = __ballot(myal);
            unsigned long long keptm = 0;
            while (rem) {
                int i = __ffsll((long long)rem) - 1;
                rem &= rem - 1;
                keptm |= 1ull << i;
                float4 ib = cbx[i];      // LDS broadcast
                float ia = car[i];
                bool kill = false;
                if ((rem >> t) & 1) {    // alive & unprocessed → t > i
                    float iwr = fminf(ib.z, cb.z) - fmaxf(ib.x, cb.x) + 1.0f;
                    float ihr = fminf(ib.w, cb.w) - fmaxf(ib.y, cb.y) + 1.0f;
                    if (iwr > 0.0f && ihr > 0.0f) {
                        float inter = iwr * ihr;
                        kill = (inter / ((ia + ca) - inter)) > NMS_T;
                    }
                }
                rem &= ~__ballot(kill);
            }
            int rank = (int)__popcll(keptm & ((1ull << t) - 1ull));
            if ((keptm >> t) & 1) {
                kbox[kept + rank] = cb;
                karea[kept + rank] = ca;
            }
            if (t == 0) skept = kept + (int)__popcll(keptm);
        }
        __syncthreads();                 // B3: kept list + count visible
    }
    int kf = skept < POST ? skept : POST;
    for (int k = t; k < POST; k += 256) {
        float4 v = (k < kf) ? kbox[k] : make_float4(0.f, 0.f, 0.f, 0.f);
        float* o = out + ((size_t)b * POST + k) * 5;
        o[0] = (float)b;
        o[1] = v.x; o[2] = v.y; o[3] = v.z; o[4] = v.w;
    }
}

extern "C" void kernel_launch(void* const* d_in, const int* in_sizes, int n_in,
                              void* d_out, int out_size, void* d_ws, size_t ws_size,
                              hipStream_t stream) {
    const float* scores  = (const float*)d_in[0];
    const float* deltas  = (const float*)d_in[1];
    const float* im_info = (const float*)d_in[2];
    const float* anchors = (const float*)d_in[3];
    float* out = (float*)d_out;

    char* ws = (char*)d_ws;
    const size_t HIST_B  = (size_t)BATCH * NSLICE * NBINS * 4;   // 4 MiB
    const size_t CNT_B   = 64;
    const size_t BKT_B   = 64;
    const size_t PAIRS_B = (size_t)BATCH * CAP * 8;              // 1 MiB
    const size_t SIDX_B  = (size_t)BATCH * PRE * 4;              // 384 KB
    uint32_t* hist = (uint32_t*)ws;
    uint32_t* cnt  = (uint32_t*)(ws + HIST_B);
    uint32_t* bkt  = (uint32_t*)(ws + HIST_B + CNT_B);
    unsigned long long* pairs = (unsigned long long*)(ws + HIST_B + CNT_B + BKT_B);
    uint32_t* sidx = (uint32_t*)(ws + HIST_B + CNT_B + BKT_B + PAIRS_B);
    float4* boxes  = (float4*)(ws + HIST_B + CNT_B + BKT_B + PAIRS_B + SIDX_B);

    hipMemsetAsync(cnt, 0, CNT_B, stream);

    k_hist<<<BATCH * NSLICE, 1024, 0, stream>>>((const float4*)scores, hist);
    k_findbucket<<<BATCH, 256, 0, stream>>>(hist, bkt);
    k_compact<<<BATCH * CBLK, 256, 0, stream>>>((const float4*)scores, bkt, cnt, pairs);
    k_sort<<<BATCH, 1024, 0, stream>>>(pairs, cnt, sidx);
    k_proposals<<<(BATCH * PRE + 255) / 256, 256, 0, stream>>>(deltas, im_info, anchors, sidx, boxes);
    k_nms<<<BATCH, 256, 0, stream>>>(boxes, out);
}

// Round 4
// 202.749 us; speedup vs baseline: 11.4978x; 1.1273x over previous
//
#include <hip/hip_runtime.h>
#include <stdint.h>

typedef unsigned long long ull;

#define BATCH 16
#define NA 9
#define HH 128
#define WW 128
#define HW (HH*WW)            // 16384
#define NITEMS (NA*HW)        // 147456 per batch
#define PRE 6000
#define POST 300
#define NMS_T 0.7f
#define NBINS 4096            // top-12 bits of sortable key
#define NSLICE 16             // histogram slices per batch
#define CAP 8192
#define CBLK 144              // compact blocks per batch (1024 items each)

__device__ __forceinline__ uint32_t fkey(float f) {
    uint32_t u = __float_as_uint(f);
    return u ^ ((u & 0x80000000u) ? 0xFFFFFFFFu : 0x80000000u);
}

// K1: per-(batch,slice) LDS histogram of top-12 key bits; non-atomic global write
__global__ __launch_bounds__(1024) void k_hist(const float4* __restrict__ scores4,
                                               uint32_t* __restrict__ hist) {
    int b = blockIdx.x / NSLICE;
    int sl = blockIdx.x % NSLICE;
    int t = threadIdx.x;
    __shared__ uint32_t lh[NBINS];
    for (int i = t; i < NBINS; i += 1024) lh[i] = 0;
    __syncthreads();
    size_t base4 = ((size_t)b * (2 * NA * HW) + (size_t)NA * HW) / 4;
    const int PER = NITEMS / NSLICE / 4;          // 2304 float4 per slice
    size_t s4 = base4 + (size_t)sl * PER;
    for (int v = t; v < PER; v += 1024) {
        float4 f = scores4[s4 + v];
        atomicAdd(&lh[fkey(f.x) >> 20], 1u);
        atomicAdd(&lh[fkey(f.y) >> 20], 1u);
        atomicAdd(&lh[fkey(f.z) >> 20], 1u);
        atomicAdd(&lh[fkey(f.w) >> 20], 1u);
    }
    __syncthreads();
    uint32_t* o = hist + ((size_t)b * NSLICE + sl) * NBINS;
    for (int i = t; i < NBINS; i += 1024) o[i] = lh[i];
}

// K2: merge slices, find bucket where cumulative-from-top crosses PRE; zero cnt
__global__ void k_findbucket(const uint32_t* __restrict__ hist, uint32_t* __restrict__ bucket,
                             uint32_t* __restrict__ cnt) {
    int b = blockIdx.x;
    int t = threadIdx.x;                          // 256 threads, 16 bins each
    if (t == 0) cnt[b] = 0;                       // runs before k_compact (stream order)
    __shared__ uint32_t csum[256];
    __shared__ uint32_t csuf[257];
    const uint32_t* hb = hist + (size_t)b * NSLICE * NBINS;
    uint32_t binv[16];
    uint32_t s = 0;
    for (int u = 0; u < 16; ++u) {
        uint32_t v = 0;
        for (int sl = 0; sl < NSLICE; ++sl) v += hb[(size_t)sl * NBINS + t * 16 + u];
        binv[u] = v; s += v;
    }
    csum[t] = s;
    __syncthreads();
    if (t == 0) {
        uint32_t acc = 0;
        csuf[256] = 0;
        for (int c = 255; c >= 0; --c) { acc += csum[c]; csuf[c] = acc; }
    }
    __syncthreads();
    uint32_t cum = csuf[t + 1];
    for (int u = 15; u >= 0; --u) {
        uint32_t c = binv[u];
        if (cum < PRE && cum + c >= PRE) bucket[b] = (uint32_t)(t * 16 + u);
        cum += c;
    }
}

// K3: compact (key, idx) pairs with bucket >= threshold; ONE global atomic per block
__global__ __launch_bounds__(256) void k_compact(const float4* __restrict__ scores4,
                                                 const uint32_t* __restrict__ bucket,
                                                 uint32_t* __restrict__ cnt,
                                                 ull* __restrict__ pairs) {
    int b = blockIdx.x / CBLK;
    int blk = blockIdx.x % CBLK;
    int t = threadIdx.x;
    int lane = t & 63, wid = t >> 6;
    uint32_t bkt = bucket[b];
    size_t base4 = ((size_t)b * (2 * NA * HW) + (size_t)NA * HW) / 4;
    float4 f = scores4[base4 + (size_t)blk * 256 + t];
    int item0 = blk * 1024 + t * 4;
    uint32_t k0 = fkey(f.x), k1 = fkey(f.y), k2 = fkey(f.z), k3 = fkey(f.w);
    bool p0 = (k0 >> 20) >= bkt, p1 = (k1 >> 20) >= bkt;
    bool p2 = (k2 >> 20) >= bkt, p3 = (k3 >> 20) >= bkt;
    ull m0 = __ballot(p0), m1 = __ballot(p1);
    ull m2 = __ballot(p2), m3 = __ballot(p3);
    uint32_t c0 = (uint32_t)__popcll(m0), c1 = (uint32_t)__popcll(m1);
    uint32_t c2 = (uint32_t)__popcll(m2), c3 = (uint32_t)__popcll(m3);
    uint32_t wcnt = c0 + c1 + c2 + c3;
    __shared__ uint32_t swc[4];
    __shared__ uint32_t sbase;
    if (lane == 0) swc[wid] = wcnt;
    __syncthreads();
    if (t == 0) {
        uint32_t a0 = swc[0], a1 = swc[1], a2 = swc[2], a3 = swc[3];
        uint32_t tot = a0 + a1 + a2 + a3;
        sbase = tot ? atomicAdd(&cnt[b], tot) : 0u;
        swc[0] = 0; swc[1] = a0; swc[2] = a0 + a1; swc[3] = a0 + a1 + a2;
    }
    __syncthreads();
    uint32_t wbase = sbase + swc[wid];
    ull below = ((ull)1 << lane) - 1ull;
    ull* pb = pairs + (size_t)b * CAP;
#define EMIT(J, K, POS) do { \
        int rem = item0 + (J); \
        int c = rem / HW; \
        int pix = rem - c * HW; \
        uint32_t idx = (uint32_t)(pix * NA + c); \
        uint32_t pos_ = (POS); \
        if (pos_ < CAP) pb[pos_] = ((ull)(K) << 32) | (uint32_t)(~idx); \
    } while (0)
    if (p0) EMIT(0, k0, wbase + (uint32_t)__popcll(m0 & below));
    if (p1) EMIT(1, k1, wbase + c0 + (uint32_t)__popcll(m1 & below));
    if (p2) EMIT(2, k2, wbase + c0 + c1 + (uint32_t)__popcll(m2 & below));
    if (p3) EMIT(3, k3, wbase + c0 + c1 + c2 + (uint32_t)__popcll(m3 & below));
#undef EMIT
}

// K4: per-batch bitonic sort (descending) of packed keys; fused decode+clip epilogue
__global__ __launch_bounds__(1024) void k_sort(const ull* __restrict__ pairs,
                                               const uint32_t* __restrict__ cnt,
                                               const float* __restrict__ deltas,
                                               const float* __restrict__ im_info,
                                               const float* __restrict__ anchors,
                                               float4* __restrict__ boxes) {
#pragma clang fp contract(off)
    int b = blockIdx.x;
    __shared__ ull s[CAP];
    int t = threadIdx.x;
    uint32_t n = cnt[b];
    if (n > CAP) n = CAP;
    for (int e = t; e < CAP; e += 1024)
        s[e] = (e < (int)n) ? pairs[(size_t)b * CAP + e] : 0ull;
    __syncthreads();
    for (int k = 2; k <= CAP; k <<= 1) {
        for (int j = k >> 1; j > 0; j >>= 1) {
            for (int p = t; p < CAP / 2; p += 1024) {
                int i = 2 * p - (p & (j - 1));
                int ix = i | j;
                ull a = s[i], c = s[ix];
                bool up = ((i & k) == 0);
                if ((a < c) == up) { s[i] = c; s[ix] = a; }
            }
            __syncthreads();
        }
    }
    // fused proposal decode + clip (was k_proposals)
    float limx = im_info[b * 3 + 1] - 1.0f;
    float limy = im_info[b * 3 + 0] - 1.0f;
    for (int e = t; e < PRE; e += 1024) {
        int idx = (int)(~((uint32_t)s[e]));
        int a = idx % NA;
        int cell = idx / NA;
        int wx = cell & (WW - 1);
        int hy = cell >> 7;
        const float* D = deltas + (size_t)b * (4 * NA * HW) + (size_t)(4 * a) * HW + hy * WW + wx;
        float dx = D[0], dy = D[HW], dw = D[2 * HW], dh = D[3 * HW];
        float ax1 = anchors[4 * a + 0], ay1 = anchors[4 * a + 1];
        float ax2 = anchors[4 * a + 2], ay2 = anchors[4 * a + 3];
        float sx = (float)(wx * 16), sy = (float)(hy * 16);
        float x1 = ax1 + sx, y1 = ay1 + sy, x2 = ax2 + sx, y2 = ay2 + sy;
        float w = x2 - x1 + 1.0f;
        float h = y2 - y1 + 1.0f;
        float cx = x1 + 0.5f * w;
        float cy = y1 + 0.5f * h;
        float pcx = dx * w + cx;
        float pcy = dy * h + cy;
        float pw = (float)exp((double)dw) * w;
        float ph = (float)exp((double)dh) * h;
        float px1 = pcx - 0.5f * pw;
        float py1 = pcy - 0.5f * ph;
        float px2 = pcx + 0.5f * pw;
        float py2 = pcy + 0.5f * ph;
        px1 = fminf(fmaxf(px1, 0.0f), limx);
        py1 = fminf(fmaxf(py1, 0.0f), limy);
        px2 = fminf(fmaxf(px2, 0.0f), limx);
        py2 = fminf(fmaxf(py2, 0.0f), limy);
        boxes[(size_t)b * PRE + e] = make_float4(px1, py1, px2, py2);
    }
}

// K6: matrix-greedy NMS. Per 64-candidate round: waves 0-3 build the 64x64
// suppression matrix (one ballot per row), waves 4-15 test candidates vs the
// kept list (kills via one ballot per wave -> no init barrier), wave 0 runs
// the greedy as pure bitmask algebra. 2 barriers/round. Exact greedy.
__global__ __launch_bounds__(1024) void k_nms(const float4* __restrict__ boxes,
                                              float* __restrict__ out) {
#pragma clang fp contract(off)
    const int b = blockIdx.x;
    const int t = threadIdx.x;
    const int lane = t & 63;
    const int wv = t >> 6;                 // 0..15
    __shared__ float4 kbox[POST + 64];     // kept boxes, index order
    __shared__ float  karea[POST + 64];
    __shared__ ull    smask[64];           // candidate-vs-candidate rows
    __shared__ ull    killm[12];           // per-wave kill ballots
    __shared__ int    skept;
    if (t == 0) skept = 0;
    __syncthreads();
    const int NR = (PRE + 63) / 64;        // 94
    for (int r = 0; r < NR; ++r) {
        int kept = skept;                  // uniform (post-barrier)
        if (kept >= POST) break;
        int c0 = r * 64;
        int c = c0 + lane;
        bool valid = (c < PRE);
        float4 cb = valid ? boxes[(size_t)b * PRE + c]
                          : make_float4(0.f, 0.f, 0.f, 0.f);
        float ca = (cb.z - cb.x + 1.0f) * (cb.w - cb.y + 1.0f);
        if (wv < 4) {
            // rows wv*16 .. wv*16+15; row box via lane-uniform load (L1 hit)
            for (int ii = 0; ii < 16; ++ii) {
                int i = wv * 16 + ii;
                int ci = c0 + i;
                float4 ib = (ci < PRE) ? boxes[(size_t)b * PRE + ci]
                                       : make_float4(0.f, 0.f, 0.f, 0.f);
                float ia = (ib.z - ib.x + 1.0f) * (ib.w - ib.y + 1.0f);
                float iwr = fminf(ib.z, cb.z) - fmaxf(ib.x, cb.x) + 1.0f;
                float ihr = fminf(ib.w, cb.w) - fmaxf(ib.y, cb.y) + 1.0f;
                bool sup = false;
                if (iwr > 0.0f && ihr > 0.0f) {        // exact: else iou == 0
                    float inter = iwr * ihr;
                    sup = (inter / ((ia + ca) - inter)) > NMS_T;
                }
                ull m = __ballot(sup);
                if (lane == ii) smask[i] = m;
            }
        } else {
            int sl = wv - 4;               // 0..11: slice of kept list
            bool killed = false;
            for (int k = sl; k < kept; k += 12) {
                float4 kb = kbox[k];       // LDS broadcast
                float iwr = fminf(kb.z, cb.z) - fmaxf(kb.x, cb.x) + 1.0f;
                float ihr = fminf(kb.w, cb.w) - fmaxf(kb.y, cb.y) + 1.0f;
                if (iwr > 0.0f && ihr > 0.0f) {
                    float inter = iwr * ihr;
                    if (inter / ((karea[k] + ca) - inter) > NMS_T) { killed = true; break; }
                }
            }
            ull km = __ballot(killed);     // unconditional -> no stale data
            if (lane == 0) killm[sl] = km;
        }
        __syncthreads();                   // B1: matrix + kills visible
        if (wv == 0) {
            ull kill = 0;
            for (int q = 0; q < 12; ++q) kill |= killm[q];   // uniform LDS reads
            ull rem = __ballot(valid) & ~kill;
            ull mymask = smask[lane];
            ull keptm = 0;
            while (rem) {                  // pure bitmask greedy
                int i = __ffsll((long long)rem) - 1;
                keptm |= 1ull << i;
                ull mi = __shfl(mymask, i);            // broadcast row i
                rem &= ~mi;                            // diag bit clears self
                rem &= ~(1ull << i);
            }
            int rank = (int)__popcll(keptm & ((1ull << lane) - 1ull));
            if ((keptm >> lane) & 1ull) {
                kbox[kept + rank] = cb;
                karea[kept + rank] = ca;
            }
            if (lane == 0) skept = kept + (int)__popcll(keptm);
        }
        __syncthreads();                   // B2: kept list + count visible
    }
    int kf = skept < POST ? skept : POST;
    for (int k = t; k < POST; k += 1024) {
        float4 v = (k < kf) ? kbox[k] : make_float4(0.f, 0.f, 0.f, 0.f);
        float* o = out + ((size_t)b * POST + k) * 5;
        o[0] = (float)b;
        o[1] = v.x; o[2] = v.y; o[3] = v.z; o[4] = v.w;
    }
}

extern "C" void kernel_launch(void* const* d_in, const int* in_sizes, int n_in,
                              void* d_out, int out_size, void* d_ws, size_t ws_size,
                              hipStream_t stream) {
    const float* scores  = (const float*)d_in[0];
    const float* deltas  = (const float*)d_in[1];
    const float* im_info = (const float*)d_in[2];
    const float* anchors = (const float*)d_in[3];
    float* out = (float*)d_out;

    char* ws = (char*)d_ws;
    const size_t HIST_B  = (size_t)BATCH * NSLICE * NBINS * 4;   // 4 MiB
    const size_t CNT_B   = 64;
    const size_t BKT_B   = 64;
    const size_t PAIRS_B = (size_t)BATCH * CAP * 8;              // 1 MiB
    uint32_t* hist = (uint32_t*)ws;
    uint32_t* cnt  = (uint32_t*)(ws + HIST_B);
    uint32_t* bkt  = (uint32_t*)(ws + HIST_B + CNT_B);
    ull* pairs     = (ull*)(ws + HIST_B + CNT_B + BKT_B);
    float4* boxes  = (float4*)(ws + HIST_B + CNT_B + BKT_B + PAIRS_B);

    k_hist<<<BATCH * NSLICE, 1024, 0, stream>>>((const float4*)scores, hist);
    k_findbucket<<<BATCH, 256, 0, stream>>>(hist, bkt, cnt);
    k_compact<<<BATCH * CBLK, 256, 0, stream>>>((const float4*)scores, bkt, cnt, pairs);
    k_sort<<<BATCH, 1024, 0, stream>>>(pairs, cnt, deltas, im_info, anchors, boxes);
    k_nms<<<BATCH, 1024, 0, stream>>>(boxes, out);
}